// Round 2
// baseline (132.188 us; speedup 1.0000x reference)
//
#include <hip/hip_runtime.h>

#define NV 13824   // 24*24*24 voxels per batch
#define CCH 64     // channels
#define NB 2       // batch

// ---------------------------------------------------------------------------
// Kernel 1: q/k/v projections.
// Block = 256 threads = 64 rows (voxels) x 4 output-quarters.
// row = t & 63 (lane-contiguous -> coalesced x loads along spatial dim),
// part = t >> 6 (wave-uniform -> LDS weight reads are broadcasts).
// ---------------------------------------------------------------------------
__global__ __launch_bounds__(256) void qkv_kernel(
    const float* __restrict__ x,
    const float* __restrict__ Wq, const float* __restrict__ bq,
    const float* __restrict__ Wk, const float* __restrict__ bk,
    const float* __restrict__ Wv, const float* __restrict__ bv,
    float* __restrict__ qo, float* __restrict__ ko, float* __restrict__ vo)
{
    __shared__ float sW[3 * 4096];
    __shared__ float sB[3 * 64];
    const int t = threadIdx.x;

    // stage weights (3 x 16KB) + biases into LDS, float4-vectorized
    {
        const float4* s0 = (const float4*)Wq;
        const float4* s1 = (const float4*)Wk;
        const float4* s2 = (const float4*)Wv;
        float4* d = (float4*)sW;
        for (int i = t; i < 1024; i += 256) {
            d[i]        = s0[i];
            d[1024 + i] = s1[i];
            d[2048 + i] = s2[i];
        }
        if (t < 64) { sB[t] = bq[t]; sB[64 + t] = bk[t]; sB[128 + t] = bv[t]; }
    }
    __syncthreads();

    const int row  = t & 63;
    const int part = t >> 6;               // 0..3, uniform within wave
    const int gr   = blockIdx.x * 64 + row; // global row 0..27647
    const int b    = gr / NV;
    const int n    = gr - b * NV;

    const float* xb = x + (size_t)b * CCH * NV + n;

    // load this row's 64 input channels into registers (coalesced: lanes = n)
    float4 xr[16];
    #pragma unroll
    for (int c4 = 0; c4 < 16; ++c4) {
        xr[c4].x = xb[(size_t)(c4 * 4 + 0) * NV];
        xr[c4].y = xb[(size_t)(c4 * 4 + 1) * NV];
        xr[c4].z = xb[(size_t)(c4 * 4 + 2) * NV];
        xr[c4].w = xb[(size_t)(c4 * 4 + 3) * NV];
    }

    const float4* wq = (const float4*)(sW + (size_t)(part * 16) * 64);
    const float4* wk = (const float4*)(sW + 4096 + (size_t)(part * 16) * 64);
    const float4* wv = (const float4*)(sW + 8192 + (size_t)(part * 16) * 64);

    float* qd = qo + (size_t)gr * 64 + part * 16;
    float* kd = ko + (size_t)gr * 64 + part * 16;
    float* vd = vo + (size_t)gr * 64 + part * 16;

    for (int oo = 0; oo < 16; ++oo) {   // rolled: scalars only, no dyn-indexed arrays
        float aq = 0.f, ak = 0.f, av = 0.f;
        #pragma unroll
        for (int c4 = 0; c4 < 16; ++c4) {
            const float4 xv = xr[c4];
            const float4 a = wq[oo * 16 + c4];   // wave-uniform -> broadcast
            aq += xv.x * a.x + xv.y * a.y + xv.z * a.z + xv.w * a.w;
            const float4 bb = wk[oo * 16 + c4];
            ak += xv.x * bb.x + xv.y * bb.y + xv.z * bb.z + xv.w * bb.w;
            const float4 cc = wv[oo * 16 + c4];
            av += xv.x * cc.x + xv.y * cc.y + xv.z * cc.z + xv.w * cc.w;
        }
        qd[oo] = aq + sB[part * 16 + oo];
        kd[oo] = ak + sB[64 + part * 16 + oo];
        vd[oo] = av + sB[128 + part * 16 + oo];
    }
}

// ---------------------------------------------------------------------------
// Kernel 2: local attention, thread = (voxel, head).
// 4 consecutive lanes = 4 heads of one voxel -> together cover the full
// contiguous 256B k/v row of a neighbor. 16 voxels/wave are consecutive n.
// OOB neighbors: logit = 0 participates in softmax (zero-padded k), v = 0.
// ---------------------------------------------------------------------------
__global__ __launch_bounds__(256) void attn_kernel(
    const float* __restrict__ x,
    const float* __restrict__ qw,
    const float* __restrict__ kw,
    const float* __restrict__ vw,
    float* __restrict__ out)
{
    const int t    = threadIdx.x;
    const int vb   = t >> 2;       // voxel within block, 0..63
    const int head = t & 3;        // 0..3
    const int gr   = blockIdx.x * 64 + vb;
    const int b    = gr / NV;
    const int n    = gr - b * NV;
    const int d    = n / 576;
    const int rem  = n - d * 576;
    const int r    = rem / 24;
    const int w    = rem - r * 24;

    // neighbor element indices (-1 if out of bounds), torch-unfold order
    int nidx[27];
    #pragma unroll
    for (int i3 = 0; i3 < 3; ++i3)
    #pragma unroll
    for (int j3 = 0; j3 < 3; ++j3)
    #pragma unroll
    for (int l3 = 0; l3 < 3; ++l3) {
        const int dd = d + i3 - 1;
        const int rr = r + j3 - 1;
        const int ww = w + l3 - 1;
        const bool ok = ((unsigned)dd < 24u) & ((unsigned)rr < 24u) & ((unsigned)ww < 24u);
        nidx[(i3 * 3 + j3) * 3 + l3] = ok ? ((dd * 24 + rr) * 24 + ww) : -1;
    }

    // load q fragment (16 floats) and pre-scale by hd^-0.5 = 0.25
    const float4* qp = (const float4*)(qw + (size_t)gr * 64 + head * 16);
    float4 q0 = qp[0], q1 = qp[1], q2 = qp[2], q3 = qp[3];
    const float s = 0.25f;
    q0.x *= s; q0.y *= s; q0.z *= s; q0.w *= s;
    q1.x *= s; q1.y *= s; q1.z *= s; q1.w *= s;
    q2.x *= s; q2.y *= s; q2.z *= s; q2.w *= s;
    q3.x *= s; q3.y *= s; q3.z *= s; q3.w *= s;

    const float* kbase = kw + (size_t)b * NV * 64 + head * 16;

    float logit[27];
    #pragma unroll
    for (int j = 0; j < 27; ++j) {
        float a = 0.f;
        if (nidx[j] >= 0) {
            const float4* kp = (const float4*)(kbase + (size_t)nidx[j] * 64);
            const float4 k0 = kp[0], k1 = kp[1], k2 = kp[2], k3 = kp[3];
            a  = q0.x * k0.x + q0.y * k0.y + q0.z * k0.z + q0.w * k0.w;
            a += q1.x * k1.x + q1.y * k1.y + q1.z * k1.z + q1.w * k1.w;
            a += q2.x * k2.x + q2.y * k2.y + q2.z * k2.z + q2.w * k2.w;
            a += q3.x * k3.x + q3.y * k3.y + q3.z * k3.z + q3.w * k3.w;
        }
        logit[j] = a;   // OOB -> 0, still participates in softmax
    }

    float m = logit[0];
    #pragma unroll
    for (int j = 1; j < 27; ++j) m = fmaxf(m, logit[j]);
    float ssum = 0.f;
    #pragma unroll
    for (int j = 0; j < 27; ++j) {
        const float e = __expf(logit[j] - m);
        logit[j] = e;
        ssum += e;
    }
    const float inv = 1.f / ssum;

    float a00=0.f,a01=0.f,a02=0.f,a03=0.f, a10=0.f,a11=0.f,a12=0.f,a13=0.f;
    float a20=0.f,a21=0.f,a22=0.f,a23=0.f, a30=0.f,a31=0.f,a32=0.f,a33=0.f;
    const float* vbase = vw + (size_t)b * NV * 64 + head * 16;
    #pragma unroll
    for (int j = 0; j < 27; ++j) {
        if (nidx[j] >= 0) {
            const float p = logit[j];
            const float4* vp = (const float4*)(vbase + (size_t)nidx[j] * 64);
            const float4 v0 = vp[0], v1 = vp[1], v2 = vp[2], v3 = vp[3];
            a00 += p * v0.x; a01 += p * v0.y; a02 += p * v0.z; a03 += p * v0.w;
            a10 += p * v1.x; a11 += p * v1.y; a12 += p * v1.z; a13 += p * v1.w;
            a20 += p * v2.x; a21 += p * v2.y; a22 += p * v2.z; a23 += p * v2.w;
            a30 += p * v3.x; a31 += p * v3.y; a32 += p * v3.z; a33 += p * v3.w;
        }
    }

    // residual add + channel-major store
    const size_t cb = (size_t)b * CCH * NV + (size_t)(head * 16) * NV + n;
    const float* xb = x + cb;
    float* ob = out + cb;
    float av[16] = {a00,a01,a02,a03,a10,a11,a12,a13,a20,a21,a22,a23,a30,a31,a32,a33};
    #pragma unroll
    for (int i = 0; i < 16; ++i) {
        ob[(size_t)i * NV] = xb[(size_t)i * NV] + av[i] * inv;
    }
}

// ---------------------------------------------------------------------------
extern "C" void kernel_launch(void* const* d_in, const int* in_sizes, int n_in,
                              void* d_out, int out_size, void* d_ws, size_t ws_size,
                              hipStream_t stream) {
    const float* x  = (const float*)d_in[0];
    // d_in[1] = cemb, unused by the reference forward
    const float* Wq = (const float*)d_in[2];
    const float* bq = (const float*)d_in[3];
    const float* Wk = (const float*)d_in[4];
    const float* bk = (const float*)d_in[5];
    const float* Wv = (const float*)d_in[6];
    const float* bv = (const float*)d_in[7];
    float* out = (float*)d_out;

    float* ws = (float*)d_ws;
    const size_t RC = (size_t)NB * NV * CCH;   // 1,769,472 floats per tensor
    float* q = ws;
    float* k = ws + RC;
    float* v = ws + 2 * RC;

    const int nrows = NB * NV;                  // 27648
    const int blocks = nrows / 64;              // 432

    qkv_kernel<<<blocks, 256, 0, stream>>>(x, Wq, bq, Wk, bk, Wv, bv, q, k, v);
    attn_kernel<<<blocks, 256, 0, stream>>>(x, q, k, v, out);
}

// Round 3
// 124.522 us; speedup vs baseline: 1.0616x; 1.0616x over previous
//
#include <hip/hip_runtime.h>

#define NV 13824   // 24*24*24 voxels per batch
#define CCH 64     // channels
#define NB 2       // batch

// ---------------------------------------------------------------------------
// Kernel 1: q/k/v projections.
// Block = 256 threads = 64 rows (voxels) x 4 output-quarters.
// Compute mapping unchanged (coalesced x loads, wave-uniform weight reads).
// NEW: outputs go through a 16KB LDS transpose buffer and are stored with
// 256-lane x float4 = 4KB fully-contiguous store instructions (round 2 showed
// 5x HBM write amplification from 256B-stride scalar stores).
// ---------------------------------------------------------------------------
__global__ __launch_bounds__(256) void qkv_kernel(
    const float* __restrict__ x,
    const float* __restrict__ Wq, const float* __restrict__ bq,
    const float* __restrict__ Wk, const float* __restrict__ bk,
    const float* __restrict__ Wv, const float* __restrict__ bv,
    float* __restrict__ qo, float* __restrict__ ko, float* __restrict__ vo)
{
    __shared__ float  sW[3 * 4096];
    __shared__ float  sB[3 * 64];
    __shared__ float4 sStage[64 * 16];   // 16KB output transpose buffer

    const int t = threadIdx.x;

    // stage weights (3 x 16KB) + biases into LDS, float4-vectorized
    {
        const float4* s0 = (const float4*)Wq;
        const float4* s1 = (const float4*)Wk;
        const float4* s2 = (const float4*)Wv;
        float4* dd = (float4*)sW;
        for (int i = t; i < 1024; i += 256) {
            dd[i]        = s0[i];
            dd[1024 + i] = s1[i];
            dd[2048 + i] = s2[i];
        }
        if (t < 64) { sB[t] = bq[t]; sB[64 + t] = bk[t]; sB[128 + t] = bv[t]; }
    }
    __syncthreads();

    const int row  = t & 63;
    const int part = t >> 6;                // 0..3, uniform within wave
    const int gr   = blockIdx.x * 64 + row; // global row 0..27647
    const int b    = gr / NV;
    const int n    = gr - b * NV;

    const float* xb = x + (size_t)b * CCH * NV + n;

    // load this row's 64 input channels into registers (coalesced: lanes = n)
    float4 xr[16];
    #pragma unroll
    for (int c4 = 0; c4 < 16; ++c4) {
        xr[c4].x = xb[(size_t)(c4 * 4 + 0) * NV];
        xr[c4].y = xb[(size_t)(c4 * 4 + 1) * NV];
        xr[c4].z = xb[(size_t)(c4 * 4 + 2) * NV];
        xr[c4].w = xb[(size_t)(c4 * 4 + 3) * NV];
    }

    float* const outs[3] = {qo, ko, vo};

    #pragma unroll
    for (int m = 0; m < 3; ++m) {
        // weight rows part*16 .. part*16+15 of matrix m (16 float4 per row)
        const float4* wm = (const float4*)(sW + m * 4096) + part * 16 * 16;
        const float*  bm = sB + m * 64 + part * 16;

        float4 o[4];
        #pragma unroll
        for (int g = 0; g < 4; ++g) {
            float a0 = 0.f, a1 = 0.f, a2 = 0.f, a3 = 0.f;
            #pragma unroll
            for (int c4 = 0; c4 < 16; ++c4) {
                const float4 xv = xr[c4];
                const float4 w0 = wm[(g * 4 + 0) * 16 + c4];  // wave-uniform
                a0 += xv.x * w0.x + xv.y * w0.y + xv.z * w0.z + xv.w * w0.w;
                const float4 w1 = wm[(g * 4 + 1) * 16 + c4];
                a1 += xv.x * w1.x + xv.y * w1.y + xv.z * w1.z + xv.w * w1.w;
                const float4 w2 = wm[(g * 4 + 2) * 16 + c4];
                a2 += xv.x * w2.x + xv.y * w2.y + xv.z * w2.z + xv.w * w2.w;
                const float4 w3 = wm[(g * 4 + 3) * 16 + c4];
                a3 += xv.x * w3.x + xv.y * w3.y + xv.z * w3.z + xv.w * w3.w;
            }
            o[g] = make_float4(a0 + bm[g * 4 + 0], a1 + bm[g * 4 + 1],
                               a2 + bm[g * 4 + 2], a3 + bm[g * 4 + 3]);
        }

        __syncthreads();   // sStage free (previous tensor's readers done)
        #pragma unroll
        for (int g = 0; g < 4; ++g) {
            // XOR swizzle at float4 granularity: bijective, spreads banks
            sStage[row * 16 + (((part * 4 + g) ^ row) & 15)] = o[g];
        }
        __syncthreads();

        // cooperative fully-coalesced store: 256 lanes x 16B = 4KB / instr
        float4* gdst = (float4*)(outs[m] + (size_t)blockIdx.x * 4096);
        #pragma unroll
        for (int s2 = 0; s2 < 4; ++s2) {
            const int j  = s2 * 256 + t;     // float4 index 0..1023
            const int rr = j >> 4;
            const int cc = j & 15;
            gdst[j] = sStage[rr * 16 + ((cc ^ rr) & 15)];
        }
    }
}

// ---------------------------------------------------------------------------
// Kernel 2: local attention, thread = (voxel, head). UNCHANGED from round 2
// (isolating the qkv store fix; attn counters land next round).
// ---------------------------------------------------------------------------
__global__ __launch_bounds__(256) void attn_kernel(
    const float* __restrict__ x,
    const float* __restrict__ qw,
    const float* __restrict__ kw,
    const float* __restrict__ vw,
    float* __restrict__ out)
{
    const int t    = threadIdx.x;
    const int vb   = t >> 2;       // voxel within block, 0..63
    const int head = t & 3;        // 0..3
    const int gr   = blockIdx.x * 64 + vb;
    const int b    = gr / NV;
    const int n    = gr - b * NV;
    const int d    = n / 576;
    const int rem  = n - d * 576;
    const int r    = rem / 24;
    const int w    = rem - r * 24;

    // neighbor element indices (-1 if out of bounds), torch-unfold order
    int nidx[27];
    #pragma unroll
    for (int i3 = 0; i3 < 3; ++i3)
    #pragma unroll
    for (int j3 = 0; j3 < 3; ++j3)
    #pragma unroll
    for (int l3 = 0; l3 < 3; ++l3) {
        const int dd = d + i3 - 1;
        const int rr = r + j3 - 1;
        const int ww = w + l3 - 1;
        const bool ok = ((unsigned)dd < 24u) & ((unsigned)rr < 24u) & ((unsigned)ww < 24u);
        nidx[(i3 * 3 + j3) * 3 + l3] = ok ? ((dd * 24 + rr) * 24 + ww) : -1;
    }

    // load q fragment (16 floats) and pre-scale by hd^-0.5 = 0.25
    const float4* qp = (const float4*)(qw + (size_t)gr * 64 + head * 16);
    float4 q0 = qp[0], q1 = qp[1], q2 = qp[2], q3 = qp[3];
    const float s = 0.25f;
    q0.x *= s; q0.y *= s; q0.z *= s; q0.w *= s;
    q1.x *= s; q1.y *= s; q1.z *= s; q1.w *= s;
    q2.x *= s; q2.y *= s; q2.z *= s; q2.w *= s;
    q3.x *= s; q3.y *= s; q3.z *= s; q3.w *= s;

    const float* kbase = kw + (size_t)b * NV * 64 + head * 16;

    float logit[27];
    #pragma unroll
    for (int j = 0; j < 27; ++j) {
        float a = 0.f;
        if (nidx[j] >= 0) {
            const float4* kp = (const float4*)(kbase + (size_t)nidx[j] * 64);
            const float4 k0 = kp[0], k1 = kp[1], k2 = kp[2], k3 = kp[3];
            a  = q0.x * k0.x + q0.y * k0.y + q0.z * k0.z + q0.w * k0.w;
            a += q1.x * k1.x + q1.y * k1.y + q1.z * k1.z + q1.w * k1.w;
            a += q2.x * k2.x + q2.y * k2.y + q2.z * k2.z + q2.w * k2.w;
            a += q3.x * k3.x + q3.y * k3.y + q3.z * k3.z + q3.w * k3.w;
        }
        logit[j] = a;   // OOB -> 0, still participates in softmax
    }

    float m = logit[0];
    #pragma unroll
    for (int j = 1; j < 27; ++j) m = fmaxf(m, logit[j]);
    float ssum = 0.f;
    #pragma unroll
    for (int j = 0; j < 27; ++j) {
        const float e = __expf(logit[j] - m);
        logit[j] = e;
        ssum += e;
    }
    const float inv = 1.f / ssum;

    float a00=0.f,a01=0.f,a02=0.f,a03=0.f, a10=0.f,a11=0.f,a12=0.f,a13=0.f;
    float a20=0.f,a21=0.f,a22=0.f,a23=0.f, a30=0.f,a31=0.f,a32=0.f,a33=0.f;
    const float* vbase = vw + (size_t)b * NV * 64 + head * 16;
    #pragma unroll
    for (int j = 0; j < 27; ++j) {
        if (nidx[j] >= 0) {
            const float p = logit[j];
            const float4* vp = (const float4*)(vbase + (size_t)nidx[j] * 64);
            const float4 v0 = vp[0], v1 = vp[1], v2 = vp[2], v3 = vp[3];
            a00 += p * v0.x; a01 += p * v0.y; a02 += p * v0.z; a03 += p * v0.w;
            a10 += p * v1.x; a11 += p * v1.y; a12 += p * v1.z; a13 += p * v1.w;
            a20 += p * v2.x; a21 += p * v2.y; a22 += p * v2.z; a23 += p * v2.w;
            a30 += p * v3.x; a31 += p * v3.y; a32 += p * v3.z; a33 += p * v3.w;
        }
    }

    // residual add + channel-major store
    const size_t cb = (size_t)b * CCH * NV + (size_t)(head * 16) * NV + n;
    const float* xb = x + cb;
    float* ob = out + cb;
    float av[16] = {a00,a01,a02,a03,a10,a11,a12,a13,a20,a21,a22,a23,a30,a31,a32,a33};
    #pragma unroll
    for (int i = 0; i < 16; ++i) {
        ob[(size_t)i * NV] = xb[(size_t)i * NV] + av[i] * inv;
    }
}

// ---------------------------------------------------------------------------
extern "C" void kernel_launch(void* const* d_in, const int* in_sizes, int n_in,
                              void* d_out, int out_size, void* d_ws, size_t ws_size,
                              hipStream_t stream) {
    const float* x  = (const float*)d_in[0];
    // d_in[1] = cemb, unused by the reference forward
    const float* Wq = (const float*)d_in[2];
    const float* bq = (const float*)d_in[3];
    const float* Wk = (const float*)d_in[4];
    const float* bk = (const float*)d_in[5];
    const float* Wv = (const float*)d_in[6];
    const float* bv = (const float*)d_in[7];
    float* out = (float*)d_out;

    float* ws = (float*)d_ws;
    const size_t RC = (size_t)NB * NV * CCH;   // 1,769,472 floats per tensor
    float* q = ws;
    float* k = ws + RC;
    float* v = ws + 2 * RC;

    const int nrows = NB * NV;                  // 27648
    const int blocks = nrows / 64;              // 432

    qkv_kernel<<<blocks, 256, 0, stream>>>(x, Wq, bq, Wk, bk, Wv, bv, q, k, v);
    attn_kernel<<<blocks, 256, 0, stream>>>(x, q, k, v, out);
}